// Round 1
// baseline (80.847 us; speedup 1.0000x reference)
//
#include <hip/hip_runtime.h>

#define B_SIZE 16384
#define K_NEG 20
#define DIM 128

// Stable log-sigmoid: logsig(x) = min(x,0) - log1p(exp(-|x|))
__device__ __forceinline__ float logsig(float x) {
    return fminf(x, 0.0f) - log1pf(__expf(-fabsf(x)));
}

__global__ __launch_bounds__(256) void skipgram_loss_kernel(
    const int* __restrict__ center,
    const int* __restrict__ target,
    const int* __restrict__ neg,
    const float* __restrict__ V,
    const float* __restrict__ U,
    float* __restrict__ accum)
{
    const int lane = threadIdx.x & 63;
    const int wid  = threadIdx.x >> 6;
    const int b    = blockIdx.x * 4 + wid;   // one wave per batch element

    float contrib = 0.0f;
    if (b < B_SIZE) {
        const int c = center[b];
        const float2 ce = ((const float2*)(V + (size_t)c * DIM))[lane];

        float part[K_NEG + 1];
        {
            const int t = target[b];
            const float2 u = ((const float2*)(U + (size_t)t * DIM))[lane];
            part[0] = ce.x * u.x + ce.y * u.y;
        }
        #pragma unroll
        for (int k = 0; k < K_NEG; ++k) {
            const int idx = neg[b * K_NEG + k];
            const float2 u = ((const float2*)(U + (size_t)idx * DIM))[lane];
            part[k + 1] = ce.x * u.x + ce.y * u.y;
        }

        // Butterfly-reduce all 21 partial dots across the 64-lane wave.
        #pragma unroll
        for (int s = 1; s < 64; s <<= 1) {
            #pragma unroll
            for (int r = 0; r <= K_NEG; ++r)
                part[r] += __shfl_xor(part[r], s, 64);
        }

        // All lanes now hold the full dot products; compute loss terms
        // redundantly wave-wide (VALU is otherwise idle).
        float acc = logsig(part[0]);            // pos_ls
        #pragma unroll
        for (int k = 1; k <= K_NEG; ++k)
            acc += logsig(-part[k]);            // sum of neg log-sigmoids
        contrib = acc;
    }

    __shared__ float ssum[4];
    if (lane == 0) ssum[wid] = contrib;
    __syncthreads();
    if (threadIdx.x == 0) {
        float s = ssum[0] + ssum[1] + ssum[2] + ssum[3];
        atomicAdd(accum, s);   // device-scope by default on CDNA
    }
}

__global__ void finalize_kernel(const float* __restrict__ accum,
                                float* __restrict__ out)
{
    out[0] = -accum[0] * (1.0f / (float)B_SIZE);
}

extern "C" void kernel_launch(void* const* d_in, const int* in_sizes, int n_in,
                              void* d_out, int out_size, void* d_ws, size_t ws_size,
                              hipStream_t stream) {
    const int*   center = (const int*)d_in[0];
    const int*   target = (const int*)d_in[1];
    const int*   neg    = (const int*)d_in[2];
    const float* V      = (const float*)d_in[3];
    const float* U      = (const float*)d_in[4];
    float* out   = (float*)d_out;
    float* accum = (float*)d_ws;

    // Zero the accumulator every call (harness does not re-poison between replays).
    hipMemsetAsync(accum, 0, sizeof(float), stream);

    skipgram_loss_kernel<<<B_SIZE / 4, 256, 0, stream>>>(center, target, neg, V, U, accum);
    finalize_kernel<<<1, 1, 0, stream>>>(accum, out);
}

// Round 2
// 46.734 us; speedup vs baseline: 1.7300x; 1.7300x over previous
//
#include <hip/hip_runtime.h>

#define B_SIZE 16384
#define K_NEG 20
#define DIM 128

// Fast stable log-sigmoid: logsig(x) = min(x,0) - log(1 + exp(-|x|)).
// t = exp(-|x|) is in (0,1], so plain log(1+t) vs log1p costs <1e-8 abs
// error -- far below the 0.29 tolerance. __expf/__logf are single
// v_exp_f32/v_log_f32 transcendentals.
__device__ __forceinline__ float logsig(float x) {
    return fminf(x, 0.0f) - __logf(1.0f + __expf(-fabsf(x)));
}

__device__ __forceinline__ float dot8(float4 a0, float4 a1, float4 b0, float4 b1) {
    return a0.x * b0.x + a0.y * b0.y + a0.z * b0.z + a0.w * b0.w
         + a1.x * b1.x + a1.y * b1.y + a1.z * b1.z + a1.w * b1.w;
}

// 4 batch elements per wave: 16 lanes per embedding row, 32 B/lane.
__global__ __launch_bounds__(256) void skipgram_loss_kernel(
    const int* __restrict__ center,
    const int* __restrict__ target,
    const int* __restrict__ neg,
    const float* __restrict__ V,
    const float* __restrict__ U,
    float* __restrict__ accum)
{
    const int tid  = threadIdx.x;
    const int lane = tid & 63;
    const int wid  = tid >> 6;
    const int sub  = lane >> 4;      // which element within the wave [0,4)
    const int sl   = lane & 15;      // slot within the 128-float row

    const int e = blockIdx.x * 16 + wid * 4 + sub;   // batch element

    // center embedding (V row): 16 lanes x 8 floats
    const int c = center[e];
    const float4* vrow = (const float4*)(V + (size_t)c * DIM);
    const float4 c0 = vrow[sl * 2];
    const float4 c1 = vrow[sl * 2 + 1];

    float part[K_NEG + 1];
    {
        const int t = target[e];
        const float4* ur = (const float4*)(U + (size_t)t * DIM);
        part[0] = dot8(c0, c1, ur[sl * 2], ur[sl * 2 + 1]);
    }
    #pragma unroll
    for (int k = 0; k < K_NEG; ++k) {
        const int idx = neg[e * K_NEG + k];
        const float4* ur = (const float4*)(U + (size_t)idx * DIM);
        part[k + 1] = dot8(c0, c1, ur[sl * 2], ur[sl * 2 + 1]);
    }

    // 4-step butterfly within each 16-lane group (xor masks < 16 stay in-group).
    #pragma unroll
    for (int s = 1; s < 16; s <<= 1) {
        #pragma unroll
        for (int r = 0; r <= K_NEG; ++r)
            part[r] += __shfl_xor(part[r], s, 64);
    }

    // Every lane of a group now holds its element's 21 full dot products.
    // One instruction stream computes logsig for all 4 elements at once.
    float acc = logsig(part[0]);
    #pragma unroll
    for (int k = 1; k <= K_NEG; ++k)
        acc += logsig(-part[k]);

    // Wave total: group leaders contribute, 2 more butterfly steps.
    float v = (sl == 0) ? acc : 0.0f;
    v += __shfl_xor(v, 16, 64);
    v += __shfl_xor(v, 32, 64);

    __shared__ float ssum[4];
    if (lane == 0) ssum[wid] = v;
    __syncthreads();
    if (tid == 0)
        atomicAdd(accum, ssum[0] + ssum[1] + ssum[2] + ssum[3]);
}

__global__ void finalize_kernel(const float* __restrict__ accum,
                                float* __restrict__ out)
{
    out[0] = -accum[0] * (1.0f / (float)B_SIZE);
}

extern "C" void kernel_launch(void* const* d_in, const int* in_sizes, int n_in,
                              void* d_out, int out_size, void* d_ws, size_t ws_size,
                              hipStream_t stream) {
    const int*   center = (const int*)d_in[0];
    const int*   target = (const int*)d_in[1];
    const int*   neg    = (const int*)d_in[2];
    const float* V      = (const float*)d_in[3];
    const float* U      = (const float*)d_in[4];
    float* out   = (float*)d_out;
    float* accum = (float*)d_ws;

    hipMemsetAsync(accum, 0, sizeof(float), stream);

    // 16 elements per 256-thread block (4 waves x 4 elements/wave)
    skipgram_loss_kernel<<<B_SIZE / 16, 256, 0, stream>>>(center, target, neg, V, U, accum);
    finalize_kernel<<<1, 1, 0, stream>>>(accum, out);
}

// Round 3
// 46.492 us; speedup vs baseline: 1.7389x; 1.0052x over previous
//
#include <hip/hip_runtime.h>

#define B_SIZE 16384
#define K_NEG 20
#define DIM 128
#define NROWS (K_NEG + 1)   // target + 20 negatives

// Fast stable log-sigmoid: logsig(x) = min(x,0) - log(1 + exp(-|x|)).
// t = exp(-|x|) in (0,1]; log vs log1p error <1e-8 abs, tolerance is 0.29.
__device__ __forceinline__ float logsig(float x) {
    return fminf(x, 0.0f) - __logf(1.0f + __expf(-fabsf(x)));
}

__device__ __forceinline__ float dot8(float4 a0, float4 a1, float4 b0, float4 b1) {
    return a0.x * b0.x + a0.y * b0.y + a0.z * b0.z + a0.w * b0.w
         + a1.x * b1.x + a1.y * b1.y + a1.z * b1.z + a1.w * b1.w;
}

// 4 batch elements per wave: 16 lanes per embedding row, 32 B/lane.
// Chunked register prefetch: 7 rows (14 float4 loads) in flight at a time.
__global__ __launch_bounds__(256) void skipgram_loss_kernel(
    const int* __restrict__ center,
    const int* __restrict__ target,
    const int* __restrict__ neg,
    const float* __restrict__ V,
    const float* __restrict__ U,
    float* __restrict__ accum)
{
    const int tid  = threadIdx.x;
    const int lane = tid & 63;
    const int wid  = tid >> 6;
    const int sub  = lane >> 4;      // element within the wave [0,4)
    const int sl   = lane & 15;      // slot within the 128-float row

    const int e = blockIdx.x * 16 + wid * 4 + sub;   // batch element

    // All row indices up front (independent loads, breaks idx->gather chain).
    int idx[NROWS];
    idx[0] = target[e];
    {
        const int* nb = neg + e * K_NEG;
        #pragma unroll
        for (int k = 0; k < K_NEG; ++k) idx[k + 1] = nb[k];
    }

    // center embedding (V row)
    const int c = center[e];
    const float4* vrow = (const float4*)(V + (size_t)c * DIM);
    const float4 c0 = vrow[sl * 2];
    const float4 c1 = vrow[sl * 2 + 1];

    float part[NROWS];
    #pragma unroll
    for (int ch = 0; ch < 3; ++ch) {            // 21 rows = 3 chunks x 7
        float4 a0[7], a1[7];
        #pragma unroll
        for (int r = 0; r < 7; ++r) {           // issue 14 independent loads
            const float4* ur = (const float4*)(U + (size_t)idx[ch * 7 + r] * DIM) + sl * 2;
            a0[r] = ur[0];
            a1[r] = ur[1];
        }
        #pragma unroll
        for (int r = 0; r < 7; ++r)             // then consume
            part[ch * 7 + r] = dot8(c0, c1, a0[r], a1[r]);
    }

    // 4-step butterfly within each 16-lane group.
    #pragma unroll
    for (int s = 1; s < 16; s <<= 1) {
        #pragma unroll
        for (int r = 0; r < NROWS; ++r)
            part[r] += __shfl_xor(part[r], s, 64);
    }

    // Each lane holds its element's 21 full dots; logsig wave-wide.
    float acc = logsig(part[0]);                // positive term
    #pragma unroll
    for (int k = 1; k < NROWS; ++k)
        acc += logsig(-part[k]);                // negative terms

    // Wave total.
    float v = (sl == 0) ? acc : 0.0f;
    v += __shfl_xor(v, 16, 64);
    v += __shfl_xor(v, 32, 64);

    __shared__ float ssum[4];
    if (lane == 0) ssum[wid] = v;
    __syncthreads();
    if (tid == 0)
        atomicAdd(accum, ssum[0] + ssum[1] + ssum[2] + ssum[3]);
}

__global__ void finalize_kernel(const float* __restrict__ accum,
                                float* __restrict__ out)
{
    out[0] = -accum[0] * (1.0f / (float)B_SIZE);
}

extern "C" void kernel_launch(void* const* d_in, const int* in_sizes, int n_in,
                              void* d_out, int out_size, void* d_ws, size_t ws_size,
                              hipStream_t stream) {
    const int*   center = (const int*)d_in[0];
    const int*   target = (const int*)d_in[1];
    const int*   neg    = (const int*)d_in[2];
    const float* V      = (const float*)d_in[3];
    const float* U      = (const float*)d_in[4];
    float* out   = (float*)d_out;
    float* accum = (float*)d_ws;

    hipMemsetAsync(accum, 0, sizeof(float), stream);

    skipgram_loss_kernel<<<B_SIZE / 16, 256, 0, stream>>>(center, target, neg, V, U, accum);
    finalize_kernel<<<1, 1, 0, stream>>>(accum, out);
}

// Round 4
// 40.509 us; speedup vs baseline: 1.9958x; 1.1477x over previous
//
#include <hip/hip_runtime.h>

#define B_SIZE 16384
#define K_NEG 20
#define DIM 128
#define NROWS (K_NEG + 1)   // target + 20 negatives
#define CHUNK 7             // rows in flight per issue group (14 dwordx4)

// Fast stable log-sigmoid: logsig(x) = min(x,0) - log(1 + exp(-|x|)).
__device__ __forceinline__ float logsig(float x) {
    return fminf(x, 0.0f) - __logf(1.0f + __expf(-fabsf(x)));
}

__device__ __forceinline__ float dot8(float4 a0, float4 a1, float4 b0, float4 b1) {
    return a0.x * b0.x + a0.y * b0.y + a0.z * b0.z + a0.w * b0.w
         + a1.x * b1.x + a1.y * b1.y + a1.z * b1.z + a1.w * b1.w;
}

// 4 batch elements per wave, 16 lanes x 32 B per row.
// Gathers issued in fenced groups of 14 so the machine scheduler cannot
// re-serialize them (VGPR must rise to hold them -> deep memory pipeline).
// __launch_bounds__(256,4): allow up to 128 VGPRs; grid supplies only
// 16 waves/CU (4/SIMD) anyway, so this costs no occupancy.
__global__ __launch_bounds__(256, 4) void skipgram_loss_kernel(
    const int* __restrict__ center,
    const int* __restrict__ target,
    const int* __restrict__ neg,
    const float* __restrict__ V,
    const float* __restrict__ U,
    float* __restrict__ accum)
{
    const int tid  = threadIdx.x;
    const int lane = tid & 63;
    const int wid  = tid >> 6;
    const int sub  = lane >> 4;      // element within the wave [0,4)
    const int sl   = lane & 15;      // slot within the 128-float row

    const int e = blockIdx.x * 16 + wid * 4 + sub;   // batch element

    // All row indices up front (breaks idx->gather dependency chains).
    int idx[NROWS];
    idx[0] = target[e];
    {
        const int* nb = neg + e * K_NEG;
        #pragma unroll
        for (int k = 0; k < K_NEG; ++k) idx[k + 1] = nb[k];
    }

    // center embedding (V row)
    const int c = center[e];
    const float4* vrow = (const float4*)(V + (size_t)c * DIM);
    const float4 c0 = vrow[sl * 2];
    const float4 c1 = vrow[sl * 2 + 1];

    float acc = 0.0f;
    #pragma unroll
    for (int ch = 0; ch < 3; ++ch) {            // 21 rows = 3 chunks x 7
        float4 a0[CHUNK], a1[CHUNK];
        #pragma unroll
        for (int r = 0; r < CHUNK; ++r) {       // issue 14 independent loads
            const float4* ur = (const float4*)(U + (size_t)idx[ch * CHUNK + r] * DIM) + sl * 2;
            a0[r] = ur[0];
            a1[r] = ur[1];
        }
        // Hard scheduling fence: nothing crosses. All 14 loads must be
        // issued (and their dests live) before any consumption below.
        __builtin_amdgcn_sched_barrier(0);

        float part[CHUNK];
        #pragma unroll
        for (int r = 0; r < CHUNK; ++r)
            part[r] = dot8(c0, c1, a0[r], a1[r]);

        // 4-step butterfly within each 16-lane group for this chunk.
        #pragma unroll
        for (int s = 1; s < 16; s <<= 1) {
            #pragma unroll
            for (int r = 0; r < CHUNK; ++r)
                part[r] += __shfl_xor(part[r], s, 64);
        }

        // Accumulate loss terms (row 0 of chunk 0 is the positive term).
        #pragma unroll
        for (int r = 0; r < CHUNK; ++r) {
            const bool positive = (ch == 0 && r == 0);
            acc += logsig(positive ? part[r] : -part[r]);
        }
    }

    // Wave total: group leaders contribute, 2 more butterfly steps.
    float v = (sl == 0) ? acc : 0.0f;
    v += __shfl_xor(v, 16, 64);
    v += __shfl_xor(v, 32, 64);

    __shared__ float ssum[4];
    if (lane == 0) ssum[wid] = v;
    __syncthreads();
    if (tid == 0)
        atomicAdd(accum, ssum[0] + ssum[1] + ssum[2] + ssum[3]);
}

__global__ void finalize_kernel(const float* __restrict__ accum,
                                float* __restrict__ out)
{
    out[0] = -accum[0] * (1.0f / (float)B_SIZE);
}

extern "C" void kernel_launch(void* const* d_in, const int* in_sizes, int n_in,
                              void* d_out, int out_size, void* d_ws, size_t ws_size,
                              hipStream_t stream) {
    const int*   center = (const int*)d_in[0];
    const int*   target = (const int*)d_in[1];
    const int*   neg    = (const int*)d_in[2];
    const float* V      = (const float*)d_in[3];
    const float* U      = (const float*)d_in[4];
    float* out   = (float*)d_out;
    float* accum = (float*)d_ws;

    hipMemsetAsync(accum, 0, sizeof(float), stream);

    skipgram_loss_kernel<<<B_SIZE / 16, 256, 0, stream>>>(center, target, neg, V, U, accum);
    finalize_kernel<<<1, 1, 0, stream>>>(accum, out);
}